// Round 1
// baseline (1013.155 us; speedup 1.0000x reference)
//
#include <hip/hip_runtime.h>
#include <hip/hip_bf16.h>
#include <cstdint>
#include <cstddef>

#define M_ROWS 65536
#define K_DIM  1024
#define N_OUT  2048

typedef __attribute__((ext_vector_type(8))) short short8;
typedef __attribute__((ext_vector_type(4))) float floatx4;

__device__ __forceinline__ unsigned short f2bf(float f) {
  unsigned int u = __float_as_uint(f);
  u += 0x7fffu + ((u >> 16) & 1u);
  return (unsigned short)(u >> 16);
}

// ---------------- Kernel 1: LayerNorm fp32 -> bf16, one wave per row --------
__global__ __launch_bounds__(256) void ln_bf16_kernel(
    const float* __restrict__ x, const float* __restrict__ gamma,
    const float* __restrict__ beta, ushort* __restrict__ xn) {
  const int wave = threadIdx.x >> 6;
  const int lane = threadIdx.x & 63;
  const size_t row = (size_t)blockIdx.x * 4 + wave;
  const float4* xr = (const float4*)(x + row * K_DIM);
  float4 v[4];
  float s = 0.f, ss = 0.f;
#pragma unroll
  for (int i = 0; i < 4; ++i) {
    v[i] = xr[lane + 64 * i];
    s  += v[i].x + v[i].y + v[i].z + v[i].w;
    ss += v[i].x * v[i].x + v[i].y * v[i].y + v[i].z * v[i].z + v[i].w * v[i].w;
  }
#pragma unroll
  for (int off = 32; off; off >>= 1) {
    s  += __shfl_xor(s, off, 64);
    ss += __shfl_xor(ss, off, 64);
  }
  const float mu = s * (1.0f / 1024.0f);
  const float rstd = rsqrtf(ss * (1.0f / 1024.0f) - mu * mu + 1e-5f);
  ushort4* orow = (ushort4*)(xn + row * K_DIM);
#pragma unroll
  for (int i = 0; i < 4; ++i) {
    const float4 g  = ((const float4*)gamma)[lane + 64 * i];
    const float4 bb = ((const float4*)beta)[lane + 64 * i];
    ushort4 o;
    o.x = f2bf((v[i].x - mu) * rstd * g.x + bb.x);
    o.y = f2bf((v[i].y - mu) * rstd * g.y + bb.y);
    o.z = f2bf((v[i].z - mu) * rstd * g.z + bb.z);
    o.w = f2bf((v[i].w - mu) * rstd * g.w + bb.w);
    orow[lane + 64 * i] = o;
  }
}

// ---------------- Kernel 2: W fp32 -> bf16 ----------------------------------
__global__ __launch_bounds__(256) void wconv_kernel(const float* __restrict__ W,
                                                    ushort* __restrict__ Wb) {
  const int i = blockIdx.x * 256 + threadIdx.x;  // one float4 per thread
  const float4 w = ((const float4*)W)[i];
  ushort4 o;
  o.x = f2bf(w.x); o.y = f2bf(w.y); o.z = f2bf(w.z); o.w = f2bf(w.w);
  ((ushort4*)Wb)[i] = o;
}

// ---------------- Kernel 3: bf16 MFMA GEMM + bias + patch-split scatter -----
// m97 structure: 128x128 tile, BK=32, 256 threads (2x2 waves, 64x64 each),
// global_load_lds width=16 staging, 4x4 16x16x32 MFMA tiles per wave.
__device__ __forceinline__ void async_copy16(const ushort* g, ushort* l) {
  __builtin_amdgcn_global_load_lds(
      (const __attribute__((address_space(1))) void*)g,
      (__attribute__((address_space(3))) void*)l, 16, 0, 0);
}

__global__ __launch_bounds__(256) void gemm_kernel(
    const ushort* __restrict__ A,   // M x K bf16 (xn)
    const ushort* __restrict__ Bw,  // N_OUT x K bf16 (W)
    const float* __restrict__ bias, float* __restrict__ out) {
  __shared__ ushort As[128 * 32];  // 8 KiB
  __shared__ ushort Bs[128 * 32];  // 8 KiB

  const int tid  = threadIdx.x;
  const int bn   = blockIdx.x;  // 16 N-tiles (fastest: same-A blocks cluster)
  const int bm   = blockIdx.y;  // 512 M-tiles
  const int lane = tid & 63;
  const int warp = tid >> 6;
  const int quad = lane >> 4;
  const int l16  = lane & 15;
  const int wm   = warp & 1;
  const int wn   = warp >> 1;

  // staging addresses: thread t loads 8 bf16 at tile (row = idx>>2, col = (idx&3)*8)
  const ushort* aG0 = A  + (size_t)(bm * 128      + (tid >> 2)) * K_DIM + (tid & 3) * 8;
  const ushort* aG1 = A  + (size_t)(bm * 128 + 64 + (tid >> 2)) * K_DIM + (tid & 3) * 8;
  const ushort* bG0 = Bw + (size_t)(bn * 128      + (tid >> 2)) * K_DIM + (tid & 3) * 8;
  const ushort* bG1 = Bw + (size_t)(bn * 128 + 64 + (tid >> 2)) * K_DIM + (tid & 3) * 8;
  ushort* lA0 = As + tid * 8;
  ushort* lA1 = As + 2048 + tid * 8;
  ushort* lB0 = Bs + tid * 8;
  ushort* lB1 = Bs + 2048 + tid * 8;

  const ushort* as_base = As + (wm * 64 + l16) * 32 + quad * 8;
  const ushort* bs_base = Bs + (wn * 64 + l16) * 32 + quad * 8;

  floatx4 acc[4][4] = {};

  for (int kt = 0; kt < K_DIM / 32; ++kt) {
    const int k0 = kt * 32;
    async_copy16(aG0 + k0, lA0);
    async_copy16(aG1 + k0, lA1);
    async_copy16(bG0 + k0, lB0);
    async_copy16(bG1 + k0, lB1);
    __syncthreads();  // compiler inserts vmcnt(0) drain

    short8 af[4], bf[4];
#pragma unroll
    for (int i = 0; i < 4; ++i) af[i] = *(const short8*)(as_base + i * 16 * 32);
#pragma unroll
    for (int i = 0; i < 4; ++i) bf[i] = *(const short8*)(bs_base + i * 16 * 32);
#pragma unroll
    for (int mi = 0; mi < 4; ++mi)
#pragma unroll
      for (int ni = 0; ni < 4; ++ni)
        acc[mi][ni] = __builtin_amdgcn_mfma_f32_16x16x32_bf16(
            af[mi], bf[ni], acc[mi][ni], 0, 0, 0);
    __syncthreads();
  }

  // epilogue: bias + patch-split scatter
  // D layout: row(m) = quad*4 + reg, col(o) = l16
  float bv[4];
#pragma unroll
  for (int ni = 0; ni < 4; ++ni)
    bv[ni] = bias[bn * 128 + wn * 64 + ni * 16 + l16];

#pragma unroll
  for (int mi = 0; mi < 4; ++mi) {
    const int mrow = bm * 128 + wm * 64 + mi * 16 + quad * 4;
#pragma unroll
    for (int r = 0; r < 4; ++r) {
      const int m = mrow + r;
      const int bnn = m >> 10;
      const int h = (m >> 5) & 31;
      const int w = m & 31;
      const size_t rowbase = (((size_t)(bnn * 64 + 2 * h)) * 64 + 2 * w) * 512;
#pragma unroll
      for (int ni = 0; ni < 4; ++ni) {
        const int o = bn * 128 + wn * 64 + ni * 16 + l16;
        const int p1 = (o >> 10) & 1;
        const int p2 = (o >> 9) & 1;
        const int f = o & 511;
        out[rowbase + (size_t)p1 * 32768 + (size_t)p2 * 512 + f] =
            acc[mi][ni][r] + bv[ni];
      }
    }
  }
}

// ---------------- Fallback (only if workspace too small): fused fp32 --------
__global__ __launch_bounds__(256) void fused_fallback(
    const float* __restrict__ x, const float* __restrict__ gamma,
    const float* __restrict__ beta, const float* __restrict__ W,
    const float* __restrict__ b, float* __restrict__ out) {
  __shared__ float xs[1024];
  __shared__ float red[8];
  const int m = blockIdx.x;
  const int t = threadIdx.x;
  const float4 v = ((const float4*)(x + (size_t)m * 1024))[t];
  float s = v.x + v.y + v.z + v.w;
  float ss = v.x * v.x + v.y * v.y + v.z * v.z + v.w * v.w;
#pragma unroll
  for (int off = 32; off; off >>= 1) {
    s  += __shfl_xor(s, off, 64);
    ss += __shfl_xor(ss, off, 64);
  }
  if ((t & 63) == 0) { red[t >> 6] = s; red[4 + (t >> 6)] = ss; }
  __syncthreads();
  const float S = red[0] + red[1] + red[2] + red[3];
  const float SS = red[4] + red[5] + red[6] + red[7];
  const float mu = S * (1.0f / 1024.0f);
  const float rstd = rsqrtf(SS * (1.0f / 1024.0f) - mu * mu + 1e-5f);
  const float4 g = ((const float4*)gamma)[t];
  const float4 be = ((const float4*)beta)[t];
  float4 xn;
  xn.x = (v.x - mu) * rstd * g.x + be.x;
  xn.y = (v.y - mu) * rstd * g.y + be.y;
  xn.z = (v.z - mu) * rstd * g.z + be.z;
  xn.w = (v.w - mu) * rstd * g.w + be.w;
  ((float4*)xs)[t] = xn;
  __syncthreads();
  const int bnn = m >> 10, h = (m >> 5) & 31, w = m & 31;
  const size_t rowbase = (((size_t)(bnn * 64 + 2 * h)) * 64 + 2 * w) * 512;
#pragma unroll 1
  for (int i = 0; i < 8; ++i) {
    const int o = t + i * 256;
    const float4* wr = (const float4*)(W + (size_t)o * 1024);
    float acc = 0.f;
    for (int k = 0; k < 256; ++k) {
      const float4 wv = wr[k];
      const float4 xv = ((const float4*)xs)[k];
      acc += wv.x * xv.x + wv.y * xv.y + wv.z * xv.z + wv.w * xv.w;
    }
    const int p1 = (o >> 10) & 1, p2 = (o >> 9) & 1, f = o & 511;
    out[rowbase + (size_t)p1 * 32768 + (size_t)p2 * 512 + f] = acc + b[o];
  }
}

extern "C" void kernel_launch(void* const* d_in, const int* in_sizes, int n_in,
                              void* d_out, int out_size, void* d_ws, size_t ws_size,
                              hipStream_t stream) {
  const float* x     = (const float*)d_in[0];
  const float* gamma = (const float*)d_in[1];
  const float* beta  = (const float*)d_in[2];
  const float* W     = (const float*)d_in[3];
  const float* b     = (const float*)d_in[4];
  float* out = (float*)d_out;

  const size_t xn_bytes = (size_t)M_ROWS * K_DIM * 2;       // 134 MB
  const size_t wb_bytes = (size_t)N_OUT * K_DIM * 2;        // 4 MB
  if (ws_size >= xn_bytes + wb_bytes) {
    ushort* xn = (ushort*)d_ws;
    ushort* Wb = (ushort*)((char*)d_ws + xn_bytes);
    ln_bf16_kernel<<<M_ROWS / 4, 256, 0, stream>>>(x, gamma, beta, xn);
    wconv_kernel<<<(N_OUT * K_DIM / 4) / 256, 256, 0, stream>>>(W, Wb);
    gemm_kernel<<<dim3(N_OUT / 128, M_ROWS / 128), 256, 0, stream>>>(xn, Wb, b, out);
  } else {
    fused_fallback<<<M_ROWS, 256, 0, stream>>>(x, gamma, beta, W, b, out);
  }
}